// Round 7
// baseline (224.715 us; speedup 1.0000x reference)
//
#include <hip/hip_runtime.h>
#include <stdint.h>

// CSSA: B=32, H=W=64, C=64, heads=4, hd=16, strip windows 64x8 -> 256 windows.
// Round 7: block=(window,head), 512 thr = 8 waves, wave = 64 queries (4 tiles).
// K streamed from global (QK A-frag == the f32x4 load; L1/L2 serve the 8 waves'
// shared 32KB head-slice). LDS = V^T only (17.3 KB). Denominator folded into the
// MFMA pipe via a ones-A-frag MFMA (no lp adds, no shuffles). (512,6): VGPR
// budget 85 -> no spill (r4/r5 lesson: forcing 8 waves/EU spills to scratch).
#define VSTR 520    // Vt row: 512 tok + 8 pad

typedef __attribute__((ext_vector_type(4))) short short4v;
typedef __attribute__((ext_vector_type(4))) float f32x4;
typedef __bf16 bf2_t __attribute__((ext_vector_type(2)));

__device__ __forceinline__ float bf2f(unsigned short u) {
    union { unsigned int i; float f; } x; x.i = ((unsigned int)u) << 16; return x.f;
}
__device__ __forceinline__ unsigned int pk2bf(float lo, float hi) {
#if __has_builtin(__builtin_amdgcn_cvt_pk_bf16_f32)
    union { bf2_t v; unsigned int u; } c;
    c.v = __builtin_amdgcn_cvt_pk_bf16_f32(lo, hi);     // 1 VALU op
    return c.u;
#else
    union { float f; unsigned int u; } a, b; a.f = lo; b.f = hi;
    return __builtin_amdgcn_perm(b.u + 0x8000u, a.u + 0x8000u, 0x07060302u);
#endif
}
__device__ __forceinline__ short4v pk4bf(float a, float b, float c, float d) {
    union { short4v s; unsigned int u[2]; } p;
    p.u[0] = pk2bf(a, b);
    p.u[1] = pk2bf(c, d);
    return p.s;
}

__global__ __launch_bounds__(512, 6)
void CSSA_69355131896243_kernel(const float* __restrict__ qkv,
                                const float* __restrict__ wconv,
                                const float* __restrict__ bconv,
                                float* __restrict__ out)
{
    __shared__ unsigned short Vt[16 * VSTR];   // 16640 B: this head's V^T[d][token]
    __shared__ float Wl[144];                  // 16 ch x 9 conv weights
    __shared__ float Bl[16];

    const int tid  = threadIdx.x;
    const int wave = tid >> 6, lane = tid & 63, quad = lane >> 4, l15 = lane & 15;

    // bid -> (window, head): head-siblings 8 apart -> same XCD under round-robin
    // dispatch -> shared Q/K/V/out 256B lines merge in L2.
    const int bid = blockIdx.x;
    const int win = (bid & 7) * 32 + (bid >> 5);
    const int h   = (bid >> 3) & 3;
    const int b   = win >> 3, wx = win & 7;

    const size_t ONE  = (size_t)32 * 4096 * 64;
    const size_t base = ((size_t)b * 4096 + (size_t)wx * 8) * 64;
    const float* gQ = qkv + base;
    const float* gK = qkv + ONE + base;
    const float* gV = qkv + 2 * ONE + base;
    const int hc = h * 16;

    // ---- stage this head's V^T as bf16: token-pair b32 writes (conflict-free) ----
    {
        const int c4 = tid & 3;          // 4-ch group within head
        const int tp = tid >> 2;         // token pair 0..127
        #pragma unroll
        for (int r = 0; r < 2; ++r) {
            const int t = r * 256 + tp * 2;
            const size_t g0 = (size_t)(t >> 3) * 4096 + (size_t)(t & 7) * 64 + hc + c4 * 4;
            const size_t g1 = (size_t)((t + 1) >> 3) * 4096 + (size_t)((t + 1) & 7) * 64 + hc + c4 * 4;
            f32x4 v0 = *(const f32x4*)(gV + g0);
            f32x4 v1 = *(const f32x4*)(gV + g1);
            #pragma unroll
            for (int j = 0; j < 4; ++j)
                *(unsigned int*)(&Vt[(c4 * 4 + j) * VSTR + t]) = pk2bf(v0[j], v1[j]);
        }
    }
    if (tid < 144) Wl[tid] = wconv[h * 144 + tid];
    if (tid < 16)  Bl[tid] = bconv[hc + tid];

    // ---- Q prefetch + pack (independent of LDS -> overlaps barrier wait) ----
    const float SCL = 0.25f * 1.44269504088896341f;   // scale*log2(e) folded in
    const int q0 = wave * 64;
    short4v qf[4];   // B[k=d=quad*4+i][n=q=l15]
    #pragma unroll
    for (int t = 0; t < 4; ++t) {
        const int q = q0 + t * 16 + l15;
        f32x4 qv = *(const f32x4*)(gQ + (size_t)(q >> 3) * 4096 + (size_t)(q & 7) * 64 + hc + quad * 4);
        qf[t] = pk4bf(qv[0] * SCL, qv[1] * SCL, qv[2] * SCL, qv[3] * SCL);
    }
    __syncthreads();

    short4v ones;   // bf16 1.0 x4: A[m][k]=1 -> D rows = column sums of B
    {
        union { short4v s; unsigned short u[4]; } o;
        o.u[0] = 0x3F80; o.u[1] = 0x3F80; o.u[2] = 0x3F80; o.u[3] = 0x3F80;
        ones = o.s;
    }

    f32x4 acc[4], accl[4];
    #pragma unroll
    for (int t = 0; t < 4; ++t) { acc[t] = (f32x4)0.0f; accl[t] = (f32x4)0.0f; }

    // ---- main loop: 32 chunks x 16 keys; K streamed from global (prefetch d1) ----
    // K A-frag: A[m=key=l15][k=d=quad*4+i] == f32x4 load of token c*16+l15.
    const float* gKh = gK + hc + quad * 4 + (size_t)(l15 >> 3) * 4096 + (size_t)(l15 & 7) * 64;
    f32x4 kv = *(const f32x4*)(gKh);
    #pragma unroll 4
    for (int c = 0; c < 32; ++c) {
        const int cn = (c + 1) & 31;                  // last iter: redundant L1 hit
        f32x4 kvn = *(const f32x4*)(gKh + (size_t)cn * 8192);
        const short4v vf = *(const short4v*)(&Vt[l15 * VSTR + c * 16 + quad * 4]);
        const short4v kf = pk4bf(kv[0], kv[1], kv[2], kv[3]);
        #pragma unroll
        for (int t = 0; t < 4; ++t) {
            // s^T[key][q]: C row=quad*4+j -> key, col=l15 -> q
            f32x4 s = __builtin_amdgcn_mfma_f32_16x16x16bf16_1k(kf, qf[t], (f32x4)0.0f, 0, 0, 0);
            const float p0 = __builtin_amdgcn_exp2f(s[0]);
            const float p1 = __builtin_amdgcn_exp2f(s[1]);
            const float p2 = __builtin_amdgcn_exp2f(s[2]);
            const float p3 = __builtin_amdgcn_exp2f(s[3]);
            const short4v pf = pk4bf(p0, p1, p2, p3);
            // P C-layout == K=16 B-frag layout -> PV straight from registers
            acc[t]  = __builtin_amdgcn_mfma_f32_16x16x16bf16_1k(vf,   pf, acc[t],  0, 0, 0);
            // denominator on the MFMA pipe: D[m][q] = sum_k P[k][q] (all rows equal)
            accl[t] = __builtin_amdgcn_mfma_f32_16x16x16bf16_1k(ones, pf, accl[t], 0, 0, 0);
        }
        kv = kvn;
    }

    float linv[4];
    #pragma unroll
    for (int t = 0; t < 4; ++t) linv[t] = __builtin_amdgcn_rcpf(accl[t][0]);

    // ---- epilogue: LePE from resident V^T, normalize, f32x4 stores ----
    #pragma unroll
    for (int j = 0; j < 4; ++j) {
        const int d = quad * 4 + j;
        float w9[9];
        #pragma unroll
        for (int o = 0; o < 9; ++o) w9[o] = Wl[d * 9 + o];
        const float bs = Bl[d];
        #pragma unroll
        for (int t = 0; t < 4; ++t) {
            const int q = q0 + t * 16 + l15;
            const int y = q >> 3, x = q & 7;
            float lep = bs;
            #pragma unroll
            for (int dy = 0; dy < 3; ++dy) {
                #pragma unroll
                for (int dx = 0; dx < 3; ++dx) {
                    const int yy = y + dy - 1, xx = x + dx - 1;
                    const bool ok = ((unsigned)yy < 64u) && ((unsigned)xx < 8u);
                    const int tt = (q + (dy - 1) * 8 + (dx - 1)) & 511;   // masked if OOB
                    lep += (ok ? w9[dy * 3 + dx] : 0.0f) * bf2f(Vt[d * VSTR + tt]);
                }
            }
            acc[t][j] = acc[t][j] * linv[t] + lep;
        }
    }
    float* gO = out + base;
    #pragma unroll
    for (int t = 0; t < 4; ++t) {
        const int q = q0 + t * 16 + l15;
        *(f32x4*)(gO + (size_t)(q >> 3) * 4096 + (size_t)(q & 7) * 64 + hc + quad * 4) = acc[t];
    }
}

extern "C" void kernel_launch(void* const* d_in, const int* in_sizes, int n_in,
                              void* d_out, int out_size, void* d_ws, size_t ws_size,
                              hipStream_t stream) {
    const float* qkv   = (const float*)d_in[0];
    const float* wconv = (const float*)d_in[1];
    const float* bconv = (const float*)d_in[2];
    float* outp = (float*)d_out;
    hipLaunchKernelGGL(CSSA_69355131896243_kernel, dim3(1024), dim3(512), 0, stream,
                       qkv, wconv, bconv, outp);
}